// Round 1
// baseline (271.599 us; speedup 1.0000x reference)
//
#include <hip/hip_runtime.h>
#include <math.h>

#define NB 16
#define PLEN 1024
#define QLEN 256
#define DIM 256
#define MASKV -10000000.0f

// ---------------- kernel 0: sp[b,p] = passage . w_p ; sq[b,q] = question . w_q
__global__ void k_rowdot(const float* __restrict__ passage,
                         const float* __restrict__ question,
                         const float* __restrict__ W,
                         float* __restrict__ sp, float* __restrict__ sq) {
  int r = blockIdx.x;
  int t = threadIdx.x;
  const float* row; const float* w; float* out; int idx;
  if (r < NB * PLEN) { row = passage + (size_t)r * DIM; w = W;        out = sp; idx = r; }
  else { r -= NB * PLEN; row = question + (size_t)r * DIM; w = W + DIM; out = sq; idx = r; }
  float v = row[t] * w[t];
  for (int o = 32; o > 0; o >>= 1) v += __shfl_down(v, o, 64);
  __shared__ float s[4];
  if ((t & 63) == 0) s[t >> 6] = v;
  __syncthreads();
  if (t == 0) out[idx] = s[0] + s[1] + s[2] + s[3];
}

// ---------------- kernel 1: S[b,p,q] = sp + sq + (passage*w_pq).question + b, masked
__global__ void k_score(const float* __restrict__ passage,
                        const float* __restrict__ question,
                        const int* __restrict__ pmask, const int* __restrict__ qmask,
                        const float* __restrict__ W, const float* __restrict__ bias,
                        const float* __restrict__ sp, const float* __restrict__ sq,
                        float* __restrict__ S) {
  int b  = blockIdx.x >> 4;
  int pt = (blockIdx.x & 15) * 64;
  int qt = blockIdx.y * 64;
  int t = threadIdx.x;
  int tx = t & 15, ty = t >> 4;
  __shared__ float As[64][17];
  __shared__ float Bs[64][17];
  const float* Ab = passage + ((size_t)b * PLEN + pt) * DIM;
  const float* Bb = question + ((size_t)b * QLEN + qt) * DIM;
  const float* wpq = W + 2 * DIM;
  float acc[4][4] = {};
  for (int kt = 0; kt < DIM; kt += 16) {
    for (int i = 0; i < 4; ++i) {
      int idx = t + i * 256;
      int rr = idx >> 4, cc = idx & 15;
      As[rr][cc] = Ab[(size_t)rr * DIM + kt + cc] * wpq[kt + cc];
      Bs[rr][cc] = Bb[(size_t)rr * DIM + kt + cc];
    }
    __syncthreads();
    for (int k = 0; k < 16; ++k) {
      float a[4], bb[4];
      for (int i = 0; i < 4; ++i) a[i] = As[ty * 4 + i][k];
      for (int j = 0; j < 4; ++j) bb[j] = Bs[tx * 4 + j][k];
      for (int i = 0; i < 4; ++i)
        for (int j = 0; j < 4; ++j) acc[i][j] += a[i] * bb[j];
    }
    __syncthreads();
  }
  float b0 = bias[0];
  for (int i = 0; i < 4; ++i) {
    int p = pt + ty * 4 + i;
    float spv = sp[b * PLEN + p];
    int pm = pmask[b * PLEN + p];
    for (int j = 0; j < 4; ++j) {
      int q = qt + tx * 4 + j;
      float v = acc[i][j] + spv + sq[b * QLEN + q] + b0;
      if (pm | qmask[b * QLEN + q]) v = MASKV;
      S[((size_t)b * PLEN + p) * QLEN + q] = v;
    }
  }
}

// ---------------- kernel 2: P2Q[b,p,:] = softmax_q(S[b,p,:]) * keep
__global__ void k_softmax_row(const float* __restrict__ S,
                              const int* __restrict__ pmask, const int* __restrict__ qmask,
                              float* __restrict__ P2Q) {
  int r = blockIdx.x;           // b*PLEN + p
  int b = r >> 10;
  int t = threadIdx.x;          // QLEN = 256
  float v = S[(size_t)r * QLEN + t];
  float m = v;
  for (int o = 32; o > 0; o >>= 1) m = fmaxf(m, __shfl_down(m, o, 64));
  __shared__ float sm[4], sl[4];
  if ((t & 63) == 0) sm[t >> 6] = m;
  __syncthreads();
  float mm = fmaxf(fmaxf(sm[0], sm[1]), fmaxf(sm[2], sm[3]));
  float e = expf(v - mm);
  float l = e;
  for (int o = 32; o > 0; o >>= 1) l += __shfl_down(l, o, 64);
  if ((t & 63) == 0) sl[t >> 6] = l;
  __syncthreads();
  float ll = sl[0] + sl[1] + sl[2] + sl[3];
  int keep = (pmask[r] == 0) & (qmask[b * QLEN + t] == 0);
  P2Q[(size_t)r * QLEN + t] = keep ? (e / ll) : 0.0f;
}

// ---------------- kernel 3: in-place column softmax over p (q2p weights, stored [b,p,q])
__global__ void k_softmax_col(float* __restrict__ S,
                              const int* __restrict__ pmask, const int* __restrict__ qmask) {
  int b  = blockIdx.x >> 4;
  int q0 = (blockIdx.x & 15) * 16;
  int t = threadIdx.x;
  int tx = t & 15;      // q within tile
  int ty = t >> 4;      // p lane (16 lanes)
  int q = q0 + tx;
  float* Sb = S + (size_t)b * PLEN * QLEN;
  float m = -3.4e38f; float l = 0.f;
  for (int p = ty; p < PLEN; p += 16) {
    float v = Sb[(size_t)p * QLEN + q];
    if (v > m) { l = l * expf(m - v); m = v; }
    l += expf(v - m);
  }
  __shared__ float ms[16][17], ls[16][17];
  ms[ty][tx] = m; ls[ty][tx] = l;
  __syncthreads();
  if (ty == 0) {
    float M = ms[0][tx], L = ls[0][tx];
    for (int i = 1; i < 16; ++i) {
      float mi = ms[i][tx], li = ls[i][tx];
      float Mn = fmaxf(M, mi);
      L = L * expf(M - Mn) + li * expf(mi - Mn);
      M = Mn;
    }
    ms[0][tx] = M; ls[0][tx] = L;
  }
  __syncthreads();
  float M = ms[0][tx], L = ls[0][tx];
  int qm = qmask[b * QLEN + q];
  for (int p = ty; p < PLEN; p += 16) {
    float v = Sb[(size_t)p * QLEN + q];
    float w = expf(v - M) / L;
    int keep = (qm == 0) & (pmask[b * PLEN + p] == 0);
    Sb[(size_t)p * QLEN + q] = keep ? w : 0.0f;
  }
}

// ---------------- kernel 4: QATT[b,q,d] = sum_p W2[b,p,q] * passage[b,p,d]
__global__ void k_q2p_att(const float* __restrict__ W2, const float* __restrict__ passage,
                          float* __restrict__ QATT) {
  int b  = blockIdx.x >> 4;
  int qt = ((blockIdx.x >> 2) & 3) * 64;
  int dt = (blockIdx.x & 3) * 64;
  int t = threadIdx.x;
  int tx = t & 15, ty = t >> 4;
  __shared__ float As[16][65];   // [p][q]
  __shared__ float Bs[16][65];   // [p][d]
  const float* Ab = W2 + (size_t)b * PLEN * QLEN;
  const float* Bb = passage + (size_t)b * PLEN * DIM;
  float acc[4][4] = {};
  for (int pt = 0; pt < PLEN; pt += 16) {
    for (int i = 0; i < 4; ++i) {
      int idx = t + i * 256;
      int rr = idx >> 6, cc = idx & 63;
      As[rr][cc] = Ab[(size_t)(pt + rr) * QLEN + qt + cc];
      Bs[rr][cc] = Bb[(size_t)(pt + rr) * DIM + dt + cc];
    }
    __syncthreads();
    for (int k = 0; k < 16; ++k) {
      float a[4], bb[4];
      for (int i = 0; i < 4; ++i) a[i] = As[k][ty * 4 + i];
      for (int j = 0; j < 4; ++j) bb[j] = Bs[k][tx * 4 + j];
      for (int i = 0; i < 4; ++i)
        for (int j = 0; j < 4; ++j) acc[i][j] += a[i] * bb[j];
    }
    __syncthreads();
  }
  for (int i = 0; i < 4; ++i) {
    int q = qt + ty * 4 + i;
    for (int j = 0; j < 4; ++j) {
      int d = dt + tx * 4 + j;
      QATT[((size_t)b * QLEN + q) * DIM + d] = acc[i][j];
    }
  }
}

// ---------------- kernel 5: out1 = P2Q @ question ; out2 = P2Q @ QATT (fused, shared A)
__global__ void k_final(const float* __restrict__ P2Q, const float* __restrict__ question,
                        const float* __restrict__ QATT, float* __restrict__ out) {
  int b  = blockIdx.x >> 6;
  int pt = ((blockIdx.x >> 2) & 15) * 64;
  int dt = (blockIdx.x & 3) * 64;
  int t = threadIdx.x;
  int tx = t & 15, ty = t >> 4;
  __shared__ float As[64][17];   // [p][q]
  __shared__ float Bq[16][65];   // [q][d]
  __shared__ float Bc[16][65];
  const float* Ab = P2Q + ((size_t)b * PLEN + pt) * QLEN;
  const float* Qb = question + (size_t)b * QLEN * DIM;
  const float* Cb = QATT + (size_t)b * QLEN * DIM;
  float acc1[4][4] = {}, acc2[4][4] = {};
  for (int kt = 0; kt < QLEN; kt += 16) {
    for (int i = 0; i < 4; ++i) {
      int idx = t + i * 256;
      int rr = idx >> 4, cc = idx & 15;
      As[rr][cc] = Ab[(size_t)rr * QLEN + kt + cc];
      int rr2 = idx >> 6, cc2 = idx & 63;
      Bq[rr2][cc2] = Qb[(size_t)(kt + rr2) * DIM + dt + cc2];
      Bc[rr2][cc2] = Cb[(size_t)(kt + rr2) * DIM + dt + cc2];
    }
    __syncthreads();
    for (int k = 0; k < 16; ++k) {
      float a[4], b1[4], b2[4];
      for (int i = 0; i < 4; ++i) a[i] = As[ty * 4 + i][k];
      for (int j = 0; j < 4; ++j) { b1[j] = Bq[k][tx * 4 + j]; b2[j] = Bc[k][tx * 4 + j]; }
      for (int i = 0; i < 4; ++i)
        for (int j = 0; j < 4; ++j) {
          acc1[i][j] += a[i] * b1[j];
          acc2[i][j] += a[i] * b2[j];
        }
    }
    __syncthreads();
  }
  float* out1 = out;
  float* out2 = out + (size_t)NB * PLEN * DIM;
  for (int i = 0; i < 4; ++i) {
    int p = pt + ty * 4 + i;
    for (int j = 0; j < 4; ++j) {
      int d = dt + tx * 4 + j;
      size_t o = ((size_t)b * PLEN + p) * DIM + d;
      out1[o] = acc1[i][j];
      out2[o] = acc2[i][j];
    }
  }
}

extern "C" void kernel_launch(void* const* d_in, const int* in_sizes, int n_in,
                              void* d_out, int out_size, void* d_ws, size_t ws_size,
                              hipStream_t stream) {
  const float* passage  = (const float*)d_in[0];
  const float* question = (const float*)d_in[1];
  const int*   pmask    = (const int*)d_in[2];
  const int*   qmask    = (const int*)d_in[3];
  const float* W        = (const float*)d_in[4];
  const float* bias     = (const float*)d_in[5];
  float* out = (float*)d_out;
  float* ws  = (float*)d_ws;

  const size_t NS = (size_t)NB * PLEN * QLEN;       // 4,194,304
  float* S    = ws;                                 // score, later reused as q2p weights
  float* P2Q  = ws + NS;
  float* QATT = ws + 2 * NS;                        // B*QLEN*DIM
  float* sp   = QATT + (size_t)NB * QLEN * DIM;
  float* sq   = sp + NB * PLEN;

  hipLaunchKernelGGL(k_rowdot, dim3(NB * PLEN + NB * QLEN), dim3(256), 0, stream,
                     passage, question, W, sp, sq);
  hipLaunchKernelGGL(k_score, dim3(NB * 16, 4), dim3(256), 0, stream,
                     passage, question, pmask, qmask, W, bias, sp, sq, S);
  hipLaunchKernelGGL(k_softmax_row, dim3(NB * PLEN), dim3(256), 0, stream,
                     S, pmask, qmask, P2Q);
  hipLaunchKernelGGL(k_softmax_col, dim3(NB * 16), dim3(256), 0, stream,
                     S, pmask, qmask);
  hipLaunchKernelGGL(k_q2p_att, dim3(NB * 16), dim3(256), 0, stream,
                     S, passage, QATT);
  hipLaunchKernelGGL(k_final, dim3(NB * 64), dim3(256), 0, stream,
                     P2Q, question, QATT, out);
}

// Round 2
// 126.152 us; speedup vs baseline: 2.1529x; 2.1529x over previous
//
#include <hip/hip_runtime.h>
#include <math.h>

#define NB 16
#define PLEN 1024
#define QLEN 256
#define DIM 256
#define MASKV -10000000.0f

typedef __attribute__((ext_vector_type(8))) short short8;
typedef __attribute__((ext_vector_type(4))) float f32x4;

__device__ inline unsigned short f2bf(float x) {
  unsigned int u = __float_as_uint(x);
  u += 0x7FFF + ((u >> 16) & 1);          // round-to-nearest-even
  return (unsigned short)(u >> 16);
}

// ---------------- k_prep: bf16 casts + row dots
// passage rows: Pw = bf16(passage * w_pq), sp = passage . w_p
// question rows: Qb = bf16(question),      sq = question . w_q
__global__ void k_prep(const float* __restrict__ passage, const float* __restrict__ question,
                       const float* __restrict__ W,
                       unsigned short* __restrict__ Pw, unsigned short* __restrict__ Qb,
                       float* __restrict__ sp, float* __restrict__ sq) {
  int wid = threadIdx.x >> 6, lane = threadIdx.x & 63;
  int row = blockIdx.x * 4 + wid;
  if (row < NB * PLEN) {
    const float* src = passage + (size_t)row * DIM;
    float s = 0.f;
    for (int j = 0; j < 4; ++j) {
      int d = lane + j * 64;
      float x = src[d];
      s += x * W[d];
      Pw[(size_t)row * DIM + d] = f2bf(x * W[2 * DIM + d]);
    }
    for (int o = 32; o > 0; o >>= 1) s += __shfl_down(s, o, 64);
    if (lane == 0) sp[row] = s;
  } else {
    int qr = row - NB * PLEN;
    const float* src = question + (size_t)qr * DIM;
    float s = 0.f;
    for (int j = 0; j < 4; ++j) {
      int d = lane + j * 64;
      float x = src[d];
      s += x * W[DIM + d];
      Qb[(size_t)qr * DIM + d] = f2bf(x);
    }
    for (int o = 32; o > 0; o >>= 1) s += __shfl_down(s, o, 64);
    if (lane == 0) sq[qr] = s;
  }
}

// ---------------- k_transpose: PbT[b,d,p] = bf16(passage[b,p,d]); QbT[b,d,q] = bf16(question[b,q,d])
__global__ void k_transpose(const float* __restrict__ passage, const float* __restrict__ question,
                            unsigned short* __restrict__ PbT, unsigned short* __restrict__ QbT) {
  int bid = blockIdx.x;
  const float* src; unsigned short* dst; int tp, td, R;
  if (bid < NB * 64) {           // passage: 16 p-tiles x 4 d-tiles
    int b = bid >> 6, ti = bid & 63;
    tp = (ti >> 2) * 64; td = (ti & 3) * 64;
    src = passage + (size_t)b * PLEN * DIM;
    dst = PbT + (size_t)b * DIM * PLEN;
    R = PLEN;
  } else {                       // question: 4 q-tiles x 4 d-tiles
    int b2 = bid - NB * 64;
    int b = b2 >> 4, ti = b2 & 15;
    tp = (ti >> 2) * 64; td = (ti & 3) * 64;
    src = question + (size_t)b * QLEN * DIM;
    dst = QbT + (size_t)b * DIM * QLEN;
    R = QLEN;
  }
  __shared__ unsigned short T[64][65];
  int t = threadIdx.x, c = t & 63, r0 = t >> 6;
  for (int k = 0; k < 16; ++k) {
    int r = r0 + 4 * k;
    T[r][c] = f2bf(src[(size_t)(tp + r) * DIM + td + c]);
  }
  __syncthreads();
  for (int k = 0; k < 16; ++k) {
    int r = r0 + 4 * k;                         // d index within tile
    dst[(size_t)(td + r) * R + tp + c] = T[c][r];
  }
}

// ---------------- k_gemm_score: S[b,p,q] = Pw @ Qb^T + sp + sq + b0, masked (fp32 out)
__global__ __launch_bounds__(256) void k_gemm_score(
    const unsigned short* __restrict__ Pw, const unsigned short* __restrict__ Qb,
    const float* __restrict__ sp, const float* __restrict__ sq,
    const int* __restrict__ pmask, const int* __restrict__ qmask,
    const float* __restrict__ bias, float* __restrict__ S) {
  int bid = blockIdx.x;
  int b = bid >> 4;
  int tm = (bid >> 1) & 7;
  int tn = bid & 1;
  const unsigned short* A  = Pw + ((size_t)b * PLEN + tm * 128) * DIM;
  const unsigned short* Bm = Qb + ((size_t)b * QLEN + tn * 128) * DIM;
  __shared__ __align__(16) unsigned short As[128][40];
  __shared__ __align__(16) unsigned short Bs[128][40];
  int t = threadIdx.x, lane = t & 63, wid = t >> 6;
  int wm = wid >> 1, wn = wid & 1;
  f32x4 acc[4][4] = {};
  int srow = t >> 2, sc = (t & 3) * 8;
  for (int kt = 0; kt < DIM; kt += 32) {
    __syncthreads();
    for (int i = 0; i < 2; ++i) {
      int r = srow + i * 64;
      *(int4*)&As[r][sc] = *(const int4*)&A[(size_t)r * DIM + kt + sc];
      *(int4*)&Bs[r][sc] = *(const int4*)&Bm[(size_t)r * DIM + kt + sc];
    }
    __syncthreads();
    short8 af[4], bf[4];
    for (int i = 0; i < 4; ++i)
      af[i] = *(const short8*)&As[wm * 64 + i * 16 + (lane & 15)][(lane >> 4) * 8];
    for (int j = 0; j < 4; ++j)
      bf[j] = *(const short8*)&Bs[wn * 64 + j * 16 + (lane & 15)][(lane >> 4) * 8];
    for (int i = 0; i < 4; ++i)
      for (int j = 0; j < 4; ++j)
        acc[i][j] = __builtin_amdgcn_mfma_f32_16x16x32_bf16(af[i], bf[j], acc[i][j], 0, 0, 0);
  }
  float b0 = bias[0];
  int p0 = tm * 128 + wm * 64, q0 = tn * 128 + wn * 64;
  for (int i = 0; i < 4; ++i)
    for (int r = 0; r < 4; ++r) {
      int p = p0 + i * 16 + (lane >> 4) * 4 + r;
      float spv = sp[b * PLEN + p] + b0;
      int pm = pmask[b * PLEN + p];
      for (int j = 0; j < 4; ++j) {
        int q = q0 + j * 16 + (lane & 15);
        float v = acc[i][j][r] + spv + sq[b * QLEN + q];
        if (pm | qmask[b * QLEN + q]) v = MASKV;
        S[((size_t)b * PLEN + p) * QLEN + q] = v;
      }
    }
}

// ---------------- k_softmax_row: P2Q[b,p,:] = bf16(softmax_q(S) * keep)
__global__ void k_softmax_row(const float* __restrict__ S,
                              const int* __restrict__ pmask, const int* __restrict__ qmask,
                              unsigned short* __restrict__ P2Q) {
  int rrow = blockIdx.x;               // b*PLEN + p
  int b = rrow >> 10;
  int t = threadIdx.x;                 // QLEN = 256
  float v = S[(size_t)rrow * QLEN + t];
  float m = v;
  for (int o = 32; o > 0; o >>= 1) m = fmaxf(m, __shfl_down(m, o, 64));
  __shared__ float sm[4], sl[4];
  if ((t & 63) == 0) sm[t >> 6] = m;
  __syncthreads();
  float mm = fmaxf(fmaxf(sm[0], sm[1]), fmaxf(sm[2], sm[3]));
  float e = __expf(v - mm);
  float l = e;
  for (int o = 32; o > 0; o >>= 1) l += __shfl_down(l, o, 64);
  if ((t & 63) == 0) sl[t >> 6] = l;
  __syncthreads();
  float inv = 1.0f / (sl[0] + sl[1] + sl[2] + sl[3]);
  int keep = (pmask[rrow] == 0) & (qmask[b * QLEN + t] == 0);
  P2Q[(size_t)rrow * QLEN + t] = f2bf(keep ? (e * inv) : 0.0f);
}

// ---------------- k_softmax_col: W2t[b,q,p] = bf16(softmax_p(S[:,q]) * keep), transposed store
__global__ void k_softmax_col(const float* __restrict__ S,
                              const int* __restrict__ pmask, const int* __restrict__ qmask,
                              unsigned short* __restrict__ W2t) {
  int b = blockIdx.x >> 4;
  int q0 = (blockIdx.x & 15) * 16;
  int t = threadIdx.x;
  int tq = t & 15, pg = t >> 4;
  int q = q0 + tq;
  const float* Sb = S + (size_t)b * PLEN * QLEN;
  float m = -3.4e38f, l = 0.f;
  for (int p = pg; p < PLEN; p += 16) {
    float v = Sb[(size_t)p * QLEN + q];
    float nm = fmaxf(m, v);
    l = l * __expf(m - nm) + __expf(v - nm);
    m = nm;
  }
  __shared__ float ms[16][17], ls[16][17];
  __shared__ float Mf[16], Lf[16];
  ms[pg][tq] = m; ls[pg][tq] = l;
  __syncthreads();
  if (pg == 0) {
    float M = ms[0][tq], L = ls[0][tq];
    for (int i = 1; i < 16; ++i) {
      float mi = ms[i][tq], li = ls[i][tq];
      float Mn = fmaxf(M, mi);
      L = L * __expf(M - Mn) + li * __expf(mi - Mn);
      M = Mn;
    }
    Mf[tq] = M; Lf[tq] = 1.0f / L;
  }
  __syncthreads();
  float M = Mf[tq], invL = Lf[tq];
  int qkeep = (qmask[b * QLEN + q] == 0);
  __shared__ float T[64][17];
  for (int p0 = 0; p0 < PLEN; p0 += 64) {
    for (int k = 0; k < 4; ++k) {
      int pr = pg + 16 * k;            // 0..63
      int p = p0 + pr;
      float v = Sb[(size_t)p * QLEN + q];
      float w = __expf(v - M) * invL;
      int keep = qkeep & (pmask[b * PLEN + p] == 0);
      T[pr][tq] = keep ? w : 0.0f;
    }
    __syncthreads();
    for (int k = 0; k < 4; ++k) {
      int qq = (t >> 6) + 4 * k;       // 0..15
      int pp = t & 63;
      W2t[((size_t)b * QLEN + q0 + qq) * PLEN + p0 + pp] = f2bf(T[pp][qq]);
    }
    __syncthreads();
  }
}

// ---------------- k_gemm_qatt: QATTt[b,d,q] = PbT @ W2t^T  (K = PLEN), bf16 out
__global__ __launch_bounds__(256) void k_gemm_qatt(
    const unsigned short* __restrict__ PbT, const unsigned short* __restrict__ W2t,
    unsigned short* __restrict__ QATTt) {
  int bid = blockIdx.x;
  int b = bid >> 4;
  int tm = (bid >> 2) & 3;
  int tn = bid & 3;
  const unsigned short* A  = PbT + ((size_t)b * DIM + tm * 64) * PLEN;
  const unsigned short* Bm = W2t + ((size_t)b * QLEN + tn * 64) * PLEN;
  __shared__ __align__(16) unsigned short As[64][72];
  __shared__ __align__(16) unsigned short Bs[64][72];
  int t = threadIdx.x, lane = t & 63, wid = t >> 6;
  int wm = wid >> 1, wn = wid & 1;
  f32x4 acc[2][2] = {};
  int srow = t >> 3, sc = (t & 7) * 8;
  for (int kt = 0; kt < PLEN; kt += 64) {
    __syncthreads();
    for (int i = 0; i < 2; ++i) {
      int r = srow + i * 32;
      *(int4*)&As[r][sc] = *(const int4*)&A[(size_t)r * PLEN + kt + sc];
      *(int4*)&Bs[r][sc] = *(const int4*)&Bm[(size_t)r * PLEN + kt + sc];
    }
    __syncthreads();
    for (int kk = 0; kk < 64; kk += 32) {
      short8 af[2], bf[2];
      for (int i = 0; i < 2; ++i)
        af[i] = *(const short8*)&As[wm * 32 + i * 16 + (lane & 15)][kk + (lane >> 4) * 8];
      for (int j = 0; j < 2; ++j)
        bf[j] = *(const short8*)&Bs[wn * 32 + j * 16 + (lane & 15)][kk + (lane >> 4) * 8];
      for (int i = 0; i < 2; ++i)
        for (int j = 0; j < 2; ++j)
          acc[i][j] = __builtin_amdgcn_mfma_f32_16x16x32_bf16(af[i], bf[j], acc[i][j], 0, 0, 0);
    }
  }
  int d0 = tm * 64 + wm * 32, q0 = tn * 64 + wn * 32;
  for (int i = 0; i < 2; ++i)
    for (int r = 0; r < 4; ++r) {
      int d = d0 + i * 16 + (lane >> 4) * 4 + r;
      for (int j = 0; j < 2; ++j) {
        int q = q0 + j * 16 + (lane & 15);
        QATTt[((size_t)b * DIM + d) * QLEN + q] = f2bf(acc[i][j][r]);
      }
    }
}

// ---------------- k_gemm_final: out1 = P2Q @ QbT^T ; out2 = P2Q @ QATTt^T (shared A)
__global__ __launch_bounds__(256) void k_gemm_final(
    const unsigned short* __restrict__ P2Q, const unsigned short* __restrict__ QbT,
    const unsigned short* __restrict__ QATTt, float* __restrict__ out) {
  int bid = blockIdx.x;
  int b = bid >> 4;
  int tm = (bid >> 1) & 7;
  int tn = bid & 1;
  const unsigned short* A  = P2Q  + ((size_t)b * PLEN + tm * 128) * QLEN;
  const unsigned short* B1 = QbT  + ((size_t)b * DIM + tn * 128) * QLEN;
  const unsigned short* B2 = QATTt + ((size_t)b * DIM + tn * 128) * QLEN;
  __shared__ __align__(16) unsigned short As[128][40];
  __shared__ __align__(16) unsigned short Bq[128][40];
  __shared__ __align__(16) unsigned short Bc[128][40];
  int t = threadIdx.x, lane = t & 63, wid = t >> 6;
  int wm = wid >> 1, wn = wid & 1;
  f32x4 acc1[4][4] = {}, acc2[4][4] = {};
  int srow = t >> 2, sc = (t & 3) * 8;
  for (int kt = 0; kt < QLEN; kt += 32) {
    __syncthreads();
    for (int i = 0; i < 2; ++i) {
      int r = srow + i * 64;
      *(int4*)&As[r][sc] = *(const int4*)&A[(size_t)r * QLEN + kt + sc];
      *(int4*)&Bq[r][sc] = *(const int4*)&B1[(size_t)r * QLEN + kt + sc];
      *(int4*)&Bc[r][sc] = *(const int4*)&B2[(size_t)r * QLEN + kt + sc];
    }
    __syncthreads();
    short8 af[4], bq[4], bc[4];
    for (int i = 0; i < 4; ++i)
      af[i] = *(const short8*)&As[wm * 64 + i * 16 + (lane & 15)][(lane >> 4) * 8];
    for (int j = 0; j < 4; ++j) {
      bq[j] = *(const short8*)&Bq[wn * 64 + j * 16 + (lane & 15)][(lane >> 4) * 8];
      bc[j] = *(const short8*)&Bc[wn * 64 + j * 16 + (lane & 15)][(lane >> 4) * 8];
    }
    for (int i = 0; i < 4; ++i)
      for (int j = 0; j < 4; ++j) {
        acc1[i][j] = __builtin_amdgcn_mfma_f32_16x16x32_bf16(af[i], bq[j], acc1[i][j], 0, 0, 0);
        acc2[i][j] = __builtin_amdgcn_mfma_f32_16x16x32_bf16(af[i], bc[j], acc2[i][j], 0, 0, 0);
      }
  }
  float* out1 = out;
  float* out2 = out + (size_t)NB * PLEN * DIM;
  int p0 = tm * 128 + wm * 64, d0 = tn * 128 + wn * 64;
  for (int i = 0; i < 4; ++i)
    for (int r = 0; r < 4; ++r) {
      int p = p0 + i * 16 + (lane >> 4) * 4 + r;
      size_t rowo = ((size_t)b * PLEN + p) * DIM;
      for (int j = 0; j < 4; ++j) {
        int d = d0 + j * 16 + (lane & 15);
        out1[rowo + d] = acc1[i][j][r];
        out2[rowo + d] = acc2[i][j][r];
      }
    }
}

extern "C" void kernel_launch(void* const* d_in, const int* in_sizes, int n_in,
                              void* d_out, int out_size, void* d_ws, size_t ws_size,
                              hipStream_t stream) {
  const float* passage  = (const float*)d_in[0];
  const float* question = (const float*)d_in[1];
  const int*   pmask    = (const int*)d_in[2];
  const int*   qmask    = (const int*)d_in[3];
  const float* W        = (const float*)d_in[4];
  const float* bias     = (const float*)d_in[5];
  float* out = (float*)d_out;

  const size_t NS = (size_t)NB * PLEN * QLEN;    // 4,194,304
  char* w = (char*)d_ws;
  float* S = (float*)w;                 w += NS * 4;
  unsigned short* Pw = (unsigned short*)w;       // reused as P2Q after gemm_score
  unsigned short* P2Q = Pw;             w += NS * 2;
  unsigned short* Qb = (unsigned short*)w;       // reused as QATTt after gemm_score
  unsigned short* QATTt = Qb;           w += (size_t)NB * QLEN * DIM * 2;
  unsigned short* PbT = (unsigned short*)w;      w += NS * 2;
  unsigned short* QbT = (unsigned short*)w;      w += (size_t)NB * DIM * QLEN * 2;
  unsigned short* W2t = (unsigned short*)w;      w += NS * 2;
  float* sp = (float*)w;                w += (size_t)NB * PLEN * 4;
  float* sq = (float*)w;

  k_prep<<<dim3((NB * (PLEN + QLEN)) / 4), dim3(256), 0, stream>>>(
      passage, question, W, Pw, Qb, sp, sq);
  k_transpose<<<dim3(NB * 64 + NB * 16), dim3(256), 0, stream>>>(
      passage, question, PbT, QbT);
  k_gemm_score<<<dim3(NB * 16), dim3(256), 0, stream>>>(
      Pw, Qb, sp, sq, pmask, qmask, bias, S);
  k_softmax_row<<<dim3(NB * PLEN), dim3(256), 0, stream>>>(
      S, pmask, qmask, P2Q);
  k_softmax_col<<<dim3(NB * 16), dim3(256), 0, stream>>>(
      S, pmask, qmask, W2t);
  k_gemm_qatt<<<dim3(NB * 16), dim3(256), 0, stream>>>(
      PbT, W2t, QATTt);
  k_gemm_final<<<dim3(NB * 16), dim3(256), 0, stream>>>(
      P2Q, QbT, QATTt, out);
}

// Round 3
// 97.834 us; speedup vs baseline: 2.7761x; 1.2895x over previous
//
#include <hip/hip_runtime.h>
#include <hip/hip_fp16.h>
#include <math.h>

#define NB 16
#define PLEN 1024
#define QLEN 256
#define DIM 256
#define MASKV -10000000.0f

typedef __attribute__((ext_vector_type(8))) short short8;
typedef __attribute__((ext_vector_type(4))) float f32x4;

__device__ inline unsigned short f2bf(float x) {
  unsigned int u = __float_as_uint(x);
  u += 0x7FFF + ((u >> 16) & 1);          // round-to-nearest-even
  return (unsigned short)(u >> 16);
}

// ---------------- k_prep: bf16 casts + row dots
__global__ void k_prep(const float* __restrict__ passage, const float* __restrict__ question,
                       const float* __restrict__ W,
                       unsigned short* __restrict__ Pw, unsigned short* __restrict__ Qb,
                       float* __restrict__ sp, float* __restrict__ sq) {
  int wid = threadIdx.x >> 6, lane = threadIdx.x & 63;
  int row = blockIdx.x * 4 + wid;
  if (row < NB * PLEN) {
    const float* src = passage + (size_t)row * DIM;
    float s = 0.f;
    for (int j = 0; j < 4; ++j) {
      int d = lane + j * 64;
      float x = src[d];
      s += x * W[d];
      Pw[(size_t)row * DIM + d] = f2bf(x * W[2 * DIM + d]);
    }
    for (int o = 32; o > 0; o >>= 1) s += __shfl_down(s, o, 64);
    if (lane == 0) sp[row] = s;
  } else {
    int qr = row - NB * PLEN;
    const float* src = question + (size_t)qr * DIM;
    float s = 0.f;
    for (int j = 0; j < 4; ++j) {
      int d = lane + j * 64;
      float x = src[d];
      s += x * W[DIM + d];
      Qb[(size_t)qr * DIM + d] = f2bf(x);
    }
    for (int o = 32; o > 0; o >>= 1) s += __shfl_down(s, o, 64);
    if (lane == 0) sq[qr] = s;
  }
}

// ---------------- k_transpose: PbT[b,d,p], QbT[b,d,q] (bf16)
__global__ void k_transpose(const float* __restrict__ passage, const float* __restrict__ question,
                            unsigned short* __restrict__ PbT, unsigned short* __restrict__ QbT) {
  int bid = blockIdx.x;
  const float* src; unsigned short* dst; int tp, td, R;
  if (bid < NB * 64) {
    int b = bid >> 6, ti = bid & 63;
    tp = (ti >> 2) * 64; td = (ti & 3) * 64;
    src = passage + (size_t)b * PLEN * DIM;
    dst = PbT + (size_t)b * DIM * PLEN;
    R = PLEN;
  } else {
    int b2 = bid - NB * 64;
    int b = b2 >> 4, ti = b2 & 15;
    tp = (ti >> 2) * 64; td = (ti & 3) * 64;
    src = question + (size_t)b * QLEN * DIM;
    dst = QbT + (size_t)b * DIM * QLEN;
    R = QLEN;
  }
  __shared__ unsigned short T[64][65];
  int t = threadIdx.x, c = t & 63, r0 = t >> 6;
  for (int k = 0; k < 16; ++k) {
    int r = r0 + 4 * k;
    T[r][c] = f2bf(src[(size_t)(tp + r) * DIM + td + c]);
  }
  __syncthreads();
  for (int k = 0; k < 16; ++k) {
    int r = r0 + 4 * k;
    dst[(size_t)(td + r) * R + tp + c] = T[c][r];
  }
}

// ---------------- k_score: S16 = masked score (fp16) + row/col softmax partials
__global__ __launch_bounds__(256) void k_score(
    const unsigned short* __restrict__ Pw, const unsigned short* __restrict__ Qb,
    const float* __restrict__ sp, const float* __restrict__ sq,
    const int* __restrict__ pmask, const int* __restrict__ qmask,
    const float* __restrict__ bias, __half* __restrict__ S16,
    float* __restrict__ RM, float* __restrict__ RL,
    float* __restrict__ CM, float* __restrict__ CL) {
  int bid = blockIdx.x;
  int b = bid >> 4;
  int tm = (bid >> 1) & 7;
  int tn = bid & 1;
  const unsigned short* A  = Pw + ((size_t)b * PLEN + tm * 128) * DIM;
  const unsigned short* Bm = Qb + ((size_t)b * QLEN + tn * 128) * DIM;
  __shared__ __align__(16) unsigned short As[128][40];
  __shared__ __align__(16) unsigned short Bs[128][40];
  __shared__ float red1[128][2];
  __shared__ float red2[128][2];
  int t = threadIdx.x, lane = t & 63, wid = t >> 6;
  int wm = wid >> 1, wn = wid & 1;
  f32x4 acc[4][4] = {};
  int srow = t >> 2, sc = (t & 3) * 8;
  for (int kt = 0; kt < DIM; kt += 32) {
    __syncthreads();
    for (int i = 0; i < 2; ++i) {
      int r = srow + i * 64;
      *(int4*)&As[r][sc] = *(const int4*)&A[(size_t)r * DIM + kt + sc];
      *(int4*)&Bs[r][sc] = *(const int4*)&Bm[(size_t)r * DIM + kt + sc];
    }
    __syncthreads();
    short8 af[4], bf[4];
    for (int i = 0; i < 4; ++i)
      af[i] = *(const short8*)&As[wm * 64 + i * 16 + (lane & 15)][(lane >> 4) * 8];
    for (int j = 0; j < 4; ++j)
      bf[j] = *(const short8*)&Bs[wn * 64 + j * 16 + (lane & 15)][(lane >> 4) * 8];
    for (int i = 0; i < 4; ++i)
      for (int j = 0; j < 4; ++j)
        acc[i][j] = __builtin_amdgcn_mfma_f32_16x16x32_bf16(af[i], bf[j], acc[i][j], 0, 0, 0);
  }
  float b0 = bias[0];
  int p0 = tm * 128 + wm * 64, q0 = tn * 128 + wn * 64;

  // -- s in-place (masked) + fp16 store
  float sqv[4]; int qm[4];
  for (int j = 0; j < 4; ++j) {
    int q = q0 + j * 16 + (lane & 15);
    sqv[j] = sq[b * QLEN + q];
    qm[j] = qmask[b * QLEN + q];
  }
  for (int i = 0; i < 4; ++i)
    for (int r = 0; r < 4; ++r) {
      int p = p0 + i * 16 + (lane >> 4) * 4 + r;
      float spv = sp[b * PLEN + p] + b0;
      int pm = pmask[b * PLEN + p];
      for (int j = 0; j < 4; ++j) {
        int q = q0 + j * 16 + (lane & 15);
        float v = acc[i][j][r] + spv + sqv[j];
        if (pm | qm[j]) v = MASKV;
        acc[i][j][r] = v;
        S16[((size_t)b * PLEN + p) * QLEN + q] = __float2half(v);
      }
    }

  // -- row partials (max,sumexp over this block's 128 q)
  float rm[4][4];
  for (int i = 0; i < 4; ++i)
    for (int r = 0; r < 4; ++r) {
      float m = fmaxf(fmaxf(acc[i][0][r], acc[i][1][r]), fmaxf(acc[i][2][r], acc[i][3][r]));
      for (int msk = 1; msk <= 8; msk <<= 1) m = fmaxf(m, __shfl_xor(m, msk, 64));
      if ((lane & 15) == 0) red1[wm * 64 + i * 16 + (lane >> 4) * 4 + r][wn] = m;
    }
  __syncthreads();
  for (int i = 0; i < 4; ++i)
    for (int r = 0; r < 4; ++r) {
      int row = wm * 64 + i * 16 + (lane >> 4) * 4 + r;
      rm[i][r] = fmaxf(red1[row][0], red1[row][1]);
    }
  for (int i = 0; i < 4; ++i)
    for (int r = 0; r < 4; ++r) {
      float s = 0.f;
      for (int j = 0; j < 4; ++j) s += __expf(acc[i][j][r] - rm[i][r]);
      for (int msk = 1; msk <= 8; msk <<= 1) s += __shfl_xor(s, msk, 64);
      if ((lane & 15) == 0) red2[wm * 64 + i * 16 + (lane >> 4) * 4 + r][wn] = s;
    }
  __syncthreads();
  if (wn == 0 && (lane & 15) == 0)
    for (int i = 0; i < 4; ++i)
      for (int r = 0; r < 4; ++r) {
        int row = wm * 64 + i * 16 + (lane >> 4) * 4 + r;
        size_t o = ((size_t)b * PLEN + tm * 128 + row) * 2 + tn;
        RM[o] = rm[i][r];
        RL[o] = red2[row][0] + red2[row][1];
      }
  __syncthreads();   // protect red1/red2 reuse

  // -- col partials (max,sumexp over this block's 128 p)
  float cm[4];
  for (int j = 0; j < 4; ++j) {
    float m = acc[0][j][0];
    for (int i = 0; i < 4; ++i)
      for (int r = 0; r < 4; ++r) m = fmaxf(m, acc[i][j][r]);
    m = fmaxf(m, __shfl_xor(m, 16, 64));
    m = fmaxf(m, __shfl_xor(m, 32, 64));
    if ((lane >> 4) == 0) red1[wn * 64 + j * 16 + (lane & 15)][wm] = m;
  }
  __syncthreads();
  for (int j = 0; j < 4; ++j) {
    int ci = wn * 64 + j * 16 + (lane & 15);
    cm[j] = fmaxf(red1[ci][0], red1[ci][1]);
  }
  for (int j = 0; j < 4; ++j) {
    float s = 0.f;
    for (int i = 0; i < 4; ++i)
      for (int r = 0; r < 4; ++r) s += __expf(acc[i][j][r] - cm[j]);
    s += __shfl_xor(s, 16, 64);
    s += __shfl_xor(s, 32, 64);
    if ((lane >> 4) == 0) red2[wn * 64 + j * 16 + (lane & 15)][wm] = s;
  }
  __syncthreads();
  if (wm == 0 && (lane >> 4) == 0)
    for (int j = 0; j < 4; ++j) {
      int ci = wn * 64 + j * 16 + (lane & 15);
      size_t o = ((size_t)b * 8 + tm) * QLEN + tn * 128 + ci;
      CM[o] = cm[j];
      CL[o] = red2[ci][0] + red2[ci][1];
    }
}

// ---------------- k_rowfinish: P2Q[p,q] = bf16(exp(s - m)/l)   (masked entries -> 0 via -inf)
__global__ void k_rowfinish(const __half* __restrict__ S16,
                            const float* __restrict__ RM, const float* __restrict__ RL,
                            unsigned short* __restrict__ P2Q) {
  int row = blockIdx.x * 4 + (threadIdx.x >> 6);
  int lane = threadIdx.x & 63;
  float m0 = RM[row * 2], m1 = RM[row * 2 + 1];
  float m = fmaxf(m0, m1);
  float inv = 1.0f / (RL[row * 2] * __expf(m0 - m) + RL[row * 2 + 1] * __expf(m1 - m));
  const __half2* src = (const __half2*)(S16 + (size_t)row * QLEN + lane * 4);
  __half2 h0 = src[0], h1 = src[1];
  float2 f0 = __half22float2(h0), f1 = __half22float2(h1);
  union { unsigned short u[4]; int2 v; } o;
  o.u[0] = f2bf(__expf(f0.x - m) * inv);
  o.u[1] = f2bf(__expf(f0.y - m) * inv);
  o.u[2] = f2bf(__expf(f1.x - m) * inv);
  o.u[3] = f2bf(__expf(f1.y - m) * inv);
  *(int2*)(P2Q + (size_t)row * QLEN + lane * 4) = o.v;
}

// ---------------- k_colfinish: W2t[b,q,p] = bf16(exp(s - M_q) / L_q), via LDS transpose
__global__ void k_colfinish(const __half* __restrict__ S16,
                            const float* __restrict__ CM, const float* __restrict__ CL,
                            unsigned short* __restrict__ W2t) {
  int bid = blockIdx.x;
  int b = bid >> 4, qt = (bid >> 2) & 3, pg = bid & 3;
  int q0 = qt * 64;
  int t = threadIdx.x;
  __shared__ float Mq[64], iLq[64];
  if (t < 64) {
    int q = q0 + t;
    float M = CM[((size_t)b * 8) * QLEN + q];
    for (int tm = 1; tm < 8; ++tm)
      M = fmaxf(M, CM[((size_t)b * 8 + tm) * QLEN + q]);
    float L = 0.f;
    for (int tm = 0; tm < 8; ++tm) {
      size_t o = ((size_t)b * 8 + tm) * QLEN + q;
      L += CL[o] * __expf(CM[o] - M);
    }
    Mq[t] = M; iLq[t] = 1.0f / L;
  }
  __syncthreads();
  __shared__ __align__(16) __half T[64][80];
  int qq = t >> 2, k4 = t & 3;
  for (int c = 0; c < 4; ++c) {
    int p0 = pg * 256 + c * 64;
    for (int k = 0; k < 2; ++k) {
      int idx = t + k * 256;
      int rr = idx >> 3, i4 = idx & 7;
      *(int4*)&T[rr][i4 * 8] =
          *(const int4*)&S16[((size_t)b * PLEN + p0 + rr) * QLEN + q0 + i4 * 8];
    }
    __syncthreads();
    float M = Mq[qq], iL = iLq[qq];
    union { unsigned short u[16]; int4 v[2]; } o;
    for (int e = 0; e < 16; ++e) {
      int pp = k4 * 16 + e;
      float s = __half2float(T[pp][qq]);
      o.u[e] = f2bf(__expf(s - M) * iL);
    }
    unsigned short* dst = W2t + ((size_t)b * QLEN + q0 + qq) * PLEN + p0 + k4 * 16;
    *(int4*)dst = o.v[0];
    *(int4*)(dst + 8) = o.v[1];
    __syncthreads();
  }
}

// ---------------- k_gemm_qatt: QATTt[b,d,q] = PbT @ W2t^T  (K = PLEN)
__global__ __launch_bounds__(256) void k_gemm_qatt(
    const unsigned short* __restrict__ PbT, const unsigned short* __restrict__ W2t,
    unsigned short* __restrict__ QATTt) {
  int bid = blockIdx.x;
  int b = bid >> 4;
  int tm = (bid >> 2) & 3;
  int tn = bid & 3;
  const unsigned short* A  = PbT + ((size_t)b * DIM + tm * 64) * PLEN;
  const unsigned short* Bm = W2t + ((size_t)b * QLEN + tn * 64) * PLEN;
  __shared__ __align__(16) unsigned short As[64][72];
  __shared__ __align__(16) unsigned short Bs[64][72];
  int t = threadIdx.x, lane = t & 63, wid = t >> 6;
  int wm = wid >> 1, wn = wid & 1;
  f32x4 acc[2][2] = {};
  int srow = t >> 3, sc = (t & 7) * 8;
  for (int kt = 0; kt < PLEN; kt += 64) {
    __syncthreads();
    for (int i = 0; i < 2; ++i) {
      int r = srow + i * 32;
      *(int4*)&As[r][sc] = *(const int4*)&A[(size_t)r * PLEN + kt + sc];
      *(int4*)&Bs[r][sc] = *(const int4*)&Bm[(size_t)r * PLEN + kt + sc];
    }
    __syncthreads();
    for (int kk = 0; kk < 64; kk += 32) {
      short8 af[2], bf[2];
      for (int i = 0; i < 2; ++i)
        af[i] = *(const short8*)&As[wm * 32 + i * 16 + (lane & 15)][kk + (lane >> 4) * 8];
      for (int j = 0; j < 2; ++j)
        bf[j] = *(const short8*)&Bs[wn * 32 + j * 16 + (lane & 15)][kk + (lane >> 4) * 8];
      for (int i = 0; i < 2; ++i)
        for (int j = 0; j < 2; ++j)
          acc[i][j] = __builtin_amdgcn_mfma_f32_16x16x32_bf16(af[i], bf[j], acc[i][j], 0, 0, 0);
    }
  }
  int d0 = tm * 64 + wm * 32, q0 = tn * 64 + wn * 32;
  for (int i = 0; i < 2; ++i)
    for (int r = 0; r < 4; ++r) {
      int d = d0 + i * 16 + (lane >> 4) * 4 + r;
      for (int j = 0; j < 2; ++j) {
        int q = q0 + j * 16 + (lane & 15);
        QATTt[((size_t)b * DIM + d) * QLEN + q] = f2bf(acc[i][j][r]);
      }
    }
}

// ---------------- k_gemm_final: out1 = P2Q @ QbT^T ; out2 = P2Q @ QATTt^T (shared A)
__global__ __launch_bounds__(256) void k_gemm_final(
    const unsigned short* __restrict__ P2Q, const unsigned short* __restrict__ QbT,
    const unsigned short* __restrict__ QATTt, float* __restrict__ out) {
  int bid = blockIdx.x;
  int b = bid >> 4;
  int tm = (bid >> 1) & 7;
  int tn = bid & 1;
  const unsigned short* A  = P2Q  + ((size_t)b * PLEN + tm * 128) * QLEN;
  const unsigned short* B1 = QbT  + ((size_t)b * DIM + tn * 128) * QLEN;
  const unsigned short* B2 = QATTt + ((size_t)b * DIM + tn * 128) * QLEN;
  __shared__ __align__(16) unsigned short As[128][40];
  __shared__ __align__(16) unsigned short Bq[128][40];
  __shared__ __align__(16) unsigned short Bc[128][40];
  int t = threadIdx.x, lane = t & 63, wid = t >> 6;
  int wm = wid >> 1, wn = wid & 1;
  f32x4 acc1[4][4] = {}, acc2[4][4] = {};
  int srow = t >> 2, sc = (t & 3) * 8;
  for (int kt = 0; kt < QLEN; kt += 32) {
    __syncthreads();
    for (int i = 0; i < 2; ++i) {
      int r = srow + i * 64;
      *(int4*)&As[r][sc] = *(const int4*)&A[(size_t)r * QLEN + kt + sc];
      *(int4*)&Bq[r][sc] = *(const int4*)&B1[(size_t)r * QLEN + kt + sc];
      *(int4*)&Bc[r][sc] = *(const int4*)&B2[(size_t)r * QLEN + kt + sc];
    }
    __syncthreads();
    short8 af[4], bq[4], bc[4];
    for (int i = 0; i < 4; ++i)
      af[i] = *(const short8*)&As[wm * 64 + i * 16 + (lane & 15)][(lane >> 4) * 8];
    for (int j = 0; j < 4; ++j) {
      bq[j] = *(const short8*)&Bq[wn * 64 + j * 16 + (lane & 15)][(lane >> 4) * 8];
      bc[j] = *(const short8*)&Bc[wn * 64 + j * 16 + (lane & 15)][(lane >> 4) * 8];
    }
    for (int i = 0; i < 4; ++i)
      for (int j = 0; j < 4; ++j) {
        acc1[i][j] = __builtin_amdgcn_mfma_f32_16x16x32_bf16(af[i], bq[j], acc1[i][j], 0, 0, 0);
        acc2[i][j] = __builtin_amdgcn_mfma_f32_16x16x32_bf16(af[i], bc[j], acc2[i][j], 0, 0, 0);
      }
  }
  float* out1 = out;
  float* out2 = out + (size_t)NB * PLEN * DIM;
  int p0 = tm * 128 + wm * 64, d0 = tn * 128 + wn * 64;
  for (int i = 0; i < 4; ++i)
    for (int r = 0; r < 4; ++r) {
      int p = p0 + i * 16 + (lane >> 4) * 4 + r;
      size_t rowo = ((size_t)b * PLEN + p) * DIM;
      for (int j = 0; j < 4; ++j) {
        int d = d0 + j * 16 + (lane & 15);
        out1[rowo + d] = acc1[i][j][r];
        out2[rowo + d] = acc2[i][j][r];
      }
    }
}

extern "C" void kernel_launch(void* const* d_in, const int* in_sizes, int n_in,
                              void* d_out, int out_size, void* d_ws, size_t ws_size,
                              hipStream_t stream) {
  const float* passage  = (const float*)d_in[0];
  const float* question = (const float*)d_in[1];
  const int*   pmask    = (const int*)d_in[2];
  const int*   qmask    = (const int*)d_in[3];
  const float* W        = (const float*)d_in[4];
  const float* bias     = (const float*)d_in[5];
  float* out = (float*)d_out;

  const size_t NS = (size_t)NB * PLEN * QLEN;    // 4,194,304
  char* w = (char*)d_ws;
  __half* S16 = (__half*)w;             w += NS * 2;
  unsigned short* Pw = (unsigned short*)w;       // reused as P2Q after k_score
  unsigned short* P2Q = Pw;             w += NS * 2;
  unsigned short* Qb = (unsigned short*)w;       // reused as QATTt after k_score
  unsigned short* QATTt = Qb;           w += (size_t)NB * QLEN * DIM * 2;
  unsigned short* PbT = (unsigned short*)w;      w += NS * 2;
  unsigned short* QbT = (unsigned short*)w;      w += (size_t)NB * DIM * QLEN * 2;
  unsigned short* W2t = (unsigned short*)w;      w += NS * 2;
  float* RM = (float*)w;                w += (size_t)NB * PLEN * 2 * 4;
  float* RL = (float*)w;                w += (size_t)NB * PLEN * 2 * 4;
  float* CM = (float*)w;                w += (size_t)NB * 8 * QLEN * 4;
  float* CL = (float*)w;                w += (size_t)NB * 8 * QLEN * 4;
  float* sp = (float*)w;                w += (size_t)NB * PLEN * 4;
  float* sq = (float*)w;

  k_prep<<<dim3((NB * (PLEN + QLEN)) / 4), dim3(256), 0, stream>>>(
      passage, question, W, Pw, Qb, sp, sq);
  k_transpose<<<dim3(NB * 64 + NB * 16), dim3(256), 0, stream>>>(
      passage, question, PbT, QbT);
  k_score<<<dim3(NB * 16), dim3(256), 0, stream>>>(
      Pw, Qb, sp, sq, pmask, qmask, bias, S16, RM, RL, CM, CL);
  k_rowfinish<<<dim3(NB * PLEN / 4), dim3(256), 0, stream>>>(
      S16, RM, RL, P2Q);
  k_colfinish<<<dim3(NB * 16), dim3(256), 0, stream>>>(
      S16, CM, CL, W2t);
  k_gemm_qatt<<<dim3(NB * 16), dim3(256), 0, stream>>>(
      PbT, W2t, QATTt);
  k_gemm_final<<<dim3(NB * 16), dim3(256), 0, stream>>>(
      P2Q, QbT, QATTt, out);
}